// Round 6
// baseline (3056.278 us; speedup 1.0000x reference)
//
#include <hip/hip_runtime.h>
#include <hip/hip_bf16.h>
#include <hip/hip_cooperative_groups.h>

#define BQ 2
#define TT 2048
#define DD 512
#define HH 8
#define LL 4
#define DFFN 2048
#define WWIN 256
#define DHD 64
#define MM (BQ*TT)   // 4096 token rows
#define NOUT (MM*DD)
#define NB 768       // cooperative grid: 3 blocks/CU x 256 CUs

typedef __attribute__((ext_vector_type(8))) short bf16x8;
typedef __attribute__((ext_vector_type(4))) float f32x4;

// ---------- helpers ----------
__device__ __forceinline__ void lds_load16(const void* g, void* l) {
  __builtin_amdgcn_global_load_lds((const __attribute__((address_space(1))) void*)g,
                                   (__attribute__((address_space(3))) void*)l,
                                   16, 0, 0);
}

// ---------- diagnostic fill ----------
__global__ __launch_bounds__(256) void fill_const(float* __restrict__ out, float C, int n) {
  int i = blockIdx.x * 256 + threadIdx.x;
  if (i < n) out[i] = C;
}

// ================= fallback-path kernels (R5 flow, unchanged) =================
__global__ __launch_bounds__(256) void prep(const float* __restrict__ tokens,
                                            float* __restrict__ x,
                                            const float* __restrict__ bq,
                                            const float* __restrict__ bk,
                                            const float* __restrict__ bv,
                                            float* __restrict__ bqkvc) {
  const int b = blockIdx.x;
  if (b < 8192) {
    int i = b * 256 + threadIdx.x;
    x[i] = tokens[i];
  } else {
    int idx = (b - 8192) * 256 + threadIdx.x;
    if (idx < LL * 1536) {
      int l = idx / 1536, n = idx % 1536;
      float v;
      if (n < 512)       v = bq[l * 512 + n];
      else if (n < 1024) v = bk[l * 512 + n - 512];
      else               v = bv[l * 512 + n - 1024];
      bqkvc[idx] = v;
    }
  }
}

__global__ __launch_bounds__(256) void transpose_all(const float* __restrict__ Wq,
                                                     const float* __restrict__ Wk,
                                                     const float* __restrict__ Wv,
                                                     const float* __restrict__ Wo,
                                                     const float* __restrict__ W1,
                                                     const float* __restrict__ W2,
                                                     __hip_bfloat16* __restrict__ wqkvT,
                                                     __hip_bfloat16* __restrict__ woT,
                                                     __hip_bfloat16* __restrict__ w1T,
                                                     __hip_bfloat16* __restrict__ w2T,
                                                     const float* __restrict__ bq,
                                                     const float* __restrict__ bk,
                                                     const float* __restrict__ bv,
                                                     float* __restrict__ bqkvc) {
  const int l = blockIdx.y;
  const int b = blockIdx.x;
  if (b >= 3072) {
    int n = (b - 3072) * 256 + threadIdx.x;
    if (n < 1536) {
      float v;
      if (n < 512)       v = bq[l * 512 + n];
      else if (n < 1024) v = bk[l * 512 + n - 512];
      else               v = bv[l * 512 + n - 1024];
      bqkvc[l * 1536 + n] = v;
    }
    return;
  }
  __shared__ float tile[32][33];
  const float* src;
  __hip_bfloat16* dst;
  int K, N, t;
  if (b < 768) {
    int which = b >> 8; t = b & 255;
    src = ((which == 0) ? Wq : (which == 1) ? Wk : Wv) + (size_t)l * 262144;
    dst = wqkvT + (size_t)l * 786432 + which * 262144;
    K = 512; N = 512;
  } else if (b < 1024) {
    t = b - 768;  src = Wo + (size_t)l * 262144;  dst = woT + (size_t)l * 262144;  K = 512; N = 512;
  } else if (b < 2048) {
    t = b - 1024; src = W1 + (size_t)l * 1048576; dst = w1T + (size_t)l * 1048576; K = 512; N = 2048;
  } else {
    t = b - 2048; src = W2 + (size_t)l * 1048576; dst = w2T + (size_t)l * 1048576; K = 2048; N = 512;
  }
  const int tilesN = N >> 5;
  const int n0 = (t % tilesN) * 32, k0 = (t / tilesN) * 32;
  const int tx = threadIdx.x & 31, ty = threadIdx.x >> 5;
#pragma unroll
  for (int r = 0; r < 32; r += 8)
    tile[ty + r][tx] = src[(size_t)(k0 + ty + r) * N + n0 + tx];
  __syncthreads();
#pragma unroll
  for (int r = 0; r < 32; r += 8)
    dst[(size_t)(n0 + ty + r) * K + k0 + tx] = __float2bfloat16(tile[tx][ty + r]);
}

__global__ __launch_bounds__(256) void ln_kernel(const float* __restrict__ x,
                                                 const float* __restrict__ g,
                                                 const float* __restrict__ b,
                                                 __hip_bfloat16* __restrict__ out) {
  const int wave = threadIdx.x >> 6, lane = threadIdx.x & 63;
  const int row = blockIdx.x * 4 + wave;
  const float* xr = x + (size_t)row * DD;
  float v[8];
  float s = 0.f;
#pragma unroll
  for (int i = 0; i < 8; ++i) { v[i] = xr[lane + i * 64]; s += v[i]; }
#pragma unroll
  for (int off = 32; off; off >>= 1) s += __shfl_xor(s, off);
  float mu = s * (1.f / DD);
  float qs = 0.f;
#pragma unroll
  for (int i = 0; i < 8; ++i) { float d = v[i] - mu; qs += d * d; }
#pragma unroll
  for (int off = 32; off; off >>= 1) qs += __shfl_xor(qs, off);
  float rstd = rsqrtf(qs * (1.f / DD) + 1e-5f);
#pragma unroll
  for (int i = 0; i < 8; ++i) {
    int c = lane + i * 64;
    out[(size_t)row * DD + c] = __float2bfloat16((v[i] - mu) * rstd * g[c] + b[c]);
  }
}

__global__ __launch_bounds__(256) void ln_f32out(const float* __restrict__ x,
                                                 const float* __restrict__ g,
                                                 const float* __restrict__ b,
                                                 float* __restrict__ out) {
  const int wave = threadIdx.x >> 6, lane = threadIdx.x & 63;
  const int row = blockIdx.x * 4 + wave;
  const float* xr = x + (size_t)row * DD;
  float v[8];
  float s = 0.f;
#pragma unroll
  for (int i = 0; i < 8; ++i) { v[i] = xr[lane + i * 64]; s += v[i]; }
#pragma unroll
  for (int off = 32; off; off >>= 1) s += __shfl_xor(s, off);
  float mu = s * (1.f / DD);
  float qs = 0.f;
#pragma unroll
  for (int i = 0; i < 8; ++i) { float d = v[i] - mu; qs += d * d; }
#pragma unroll
  for (int off = 32; off; off >>= 1) qs += __shfl_xor(qs, off);
  float rstd = rsqrtf(qs * (1.f / DD) + 1e-5f);
#pragma unroll
  for (int i = 0; i < 8; ++i) {
    int c = lane + i * 64;
    out[(size_t)row * DD + c] = (v[i] - mu) * rstd * g[c] + b[c];
  }
}

enum { EPI_BF16 = 0, EPI_GELU = 1, EPI_ADDF32 = 2, EPI_RES = 3 };

template <int EPI, bool ROPE, int BM, int BN>
__global__ __launch_bounds__(256, 1) void gemm_bt(const __hip_bfloat16* __restrict__ A,
                                                  const __hip_bfloat16* __restrict__ BT,
                                                  const float* __restrict__ bias,
                                                  __hip_bfloat16* __restrict__ Obf,
                                                  float* __restrict__ Of,
                                                  const float* __restrict__ Orin,
                                                  __hip_bfloat16* __restrict__ VTo,
                                                  int M, int N, int K, int KS,
                                                  int ostride, int ooff) {
  constexpr int MI = (BM == 64) ? 2 : ((BN == 128) ? 4 : 2);
  constexpr int NJ = (BM == 64) ? 2 : 4;
  __shared__ __align__(16) __hip_bfloat16 Ash[2][2][BM * 32];
  __shared__ __align__(16) __hip_bfloat16 Bsh[2][2][BN * 32];
  const int tid = threadIdx.x;
  const int wave = tid >> 6;
  const int lane = tid & 63;
  const int m0 = blockIdx.y * BM;
  const int n0 = blockIdx.x * BN;
  const int kbase = blockIdx.z * KS;
  const int wm = (BM == 64) ? ((wave >> 1) * 32)
                            : ((BN == 128) ? ((wave >> 1) * 64) : (wave * 32));
  const int wn = (BM == 64) ? ((wave & 1) * 32)
                            : ((BN == 128) ? ((wave & 1) * 64) : 0);
  const int l15 = lane & 15;
  const int quad = lane >> 4;

  f32x4 acc[MI][NJ] = {};

  const int r0 = tid >> 2;
  const int o0 = (tid & 3) * 8;

  const __hip_bfloat16* Ap0 = A + (size_t)(m0 + r0) * K + kbase + o0;
  const __hip_bfloat16* Ap1 = Ap0 + (size_t)64 * K;
  const __hip_bfloat16* Bp0 = BT + (size_t)(n0 + r0) * K + kbase + o0;
  const __hip_bfloat16* Bp1 = Bp0 + (size_t)64 * K;

  auto stage64 = [&](int buf, int k) {
    lds_load16(Ap0 + k,      &Ash[buf][0][wave * 512]);
    lds_load16(Ap0 + k + 32, &Ash[buf][1][wave * 512]);
    if constexpr (BM == 128) {
      lds_load16(Ap1 + k,      &Ash[buf][0][2048 + wave * 512]);
      lds_load16(Ap1 + k + 32, &Ash[buf][1][2048 + wave * 512]);
    }
    lds_load16(Bp0 + k,      &Bsh[buf][0][wave * 512]);
    lds_load16(Bp0 + k + 32, &Bsh[buf][1][wave * 512]);
    if constexpr (BN == 128) {
      lds_load16(Bp1 + k,      &Bsh[buf][0][2048 + wave * 512]);
      lds_load16(Bp1 + k + 32, &Bsh[buf][1][2048 + wave * 512]);
    }
  };
  auto compute = [&](const __hip_bfloat16* As, const __hip_bfloat16* Bs) {
    bf16x8 af[MI], bfr[NJ];
#pragma unroll
    for (int i = 0; i < MI; ++i)
      af[i] = *(const bf16x8*)&As[(wm + i * 16 + l15) * 32 + quad * 8];
#pragma unroll
    for (int j = 0; j < NJ; ++j)
      bfr[j] = *(const bf16x8*)&Bs[(wn + j * 16 + l15) * 32 + quad * 8];
#pragma unroll
    for (int i = 0; i < MI; ++i)
#pragma unroll
      for (int j = 0; j < NJ; ++j)
        acc[i][j] = __builtin_amdgcn_mfma_f32_16x16x32_bf16(af[i], bfr[j], acc[i][j], 0, 0, 0);
  };
  auto compute64 = [&](int buf) {
    compute(Ash[buf][0], Bsh[buf][0]);
    compute(Ash[buf][1], Bsh[buf][1]);
  };

  stage64(0, 0);
  for (int k0 = 0; k0 < KS; k0 += 128) {
    __syncthreads();
    if (k0 + 64 < KS) stage64(1, k0 + 64);
    compute64(0);
    __syncthreads();
    if (k0 + 128 < KS) stage64(0, k0 + 128);
    compute64(1);
  }

  if constexpr (ROPE) {
    if (n0 < 1024) {
#pragma unroll
      for (int j = 0; j < 2; ++j) {
        const int col = n0 + wn + j * 16 + l15;
        const float bv0 = bias[col], bv1 = bias[col + 32];
        const float freq = __powf(10000.f, -(float)(j * 16 + l15) * (1.f / 32.f));
#pragma unroll
        for (int i = 0; i < MI; ++i) {
          const int row = m0 + wm + i * 16 + quad * 4;
#pragma unroll
          for (int r = 0; r < 4; ++r) {
            const int t = (row + r) & 2047;
            float sn, cs;
            __sincosf((float)t * freq, &sn, &cs);
            const float a0 = acc[i][j][r] + bv0;
            const float a1 = acc[i][j + 2][r] + bv1;
            const size_t idx = (size_t)(row + r) * ostride + ooff + col;
            Obf[idx]      = __float2bfloat16(a0 * cs - a1 * sn);
            Obf[idx + 32] = __float2bfloat16(a1 * cs + a0 * sn);
          }
        }
      }
    } else {
#pragma unroll
      for (int j = 0; j < NJ; ++j) {
        const int col = n0 + wn + j * 16 + l15;
        const float bv = bias[col];
        const int d = col - 1024;
#pragma unroll
        for (int i = 0; i < MI; ++i) {
          const int row = m0 + wm + i * 16 + quad * 4;
#pragma unroll
          for (int r = 0; r < 4; ++r)
            VTo[(size_t)d * 4096 + row + r] = __float2bfloat16(acc[i][j][r] + bv);
        }
      }
    }
    return;
  }

#pragma unroll
  for (int j = 0; j < NJ; ++j) {
    const int col = n0 + wn + j * 16 + l15;
    const float bv = (EPI == EPI_RES || blockIdx.z == 0) ? bias[col] : 0.f;
#pragma unroll
    for (int i = 0; i < MI; ++i) {
      const int row = m0 + wm + i * 16 + quad * 4;
#pragma unroll
      for (int r = 0; r < 4; ++r) {
        float v = acc[i][j][r] + bv;
        size_t idx = (size_t)(row + r) * ostride + ooff + col;
        if (EPI == EPI_BF16) {
          Obf[idx] = __float2bfloat16(v);
        } else if (EPI == EPI_GELU) {
          float ge = 0.5f * v * (1.f + erff(v * 0.70710678118654752f));
          Obf[idx] = __float2bfloat16(ge);
        } else if (EPI == EPI_RES) {
          Of[idx] = Orin[idx] + v;
        } else {
          atomicAdd(&Of[idx], v);
        }
      }
    }
  }
}

__global__ __launch_bounds__(256, 1) void attn_mfma(const __hip_bfloat16* __restrict__ qkv,
                                                    const __hip_bfloat16* __restrict__ VT,
                                                    __hip_bfloat16* __restrict__ ao) {
  constexpr int KPAD = 72;
  constexpr int PPAD = 40;
  __shared__ __align__(16) __hip_bfloat16 Ksh[320 * KPAD];
  __shared__ __align__(16) __hip_bfloat16 Psh[4 * 16 * PPAD];
  const int tid = threadIdx.x;
  const int wave = tid >> 6;
  const int lane = tid & 63;
  const int l15 = lane & 15;
  const int quad = lane >> 4;
  const int bh = blockIdx.y;
  const int b = bh >> 3, h = bh & 7;
  const int q0 = blockIdx.x * 64;
  const int j0 = (q0 >= WWIN) ? (q0 - WWIN) : 0;
  const int nk = (q0 + 63) - j0 + 1;

  const size_t baseK = ((size_t)(b * TT + j0)) * 1536 + 512 + h * 64;
  for (int c = tid; c < nk * 8; c += 256) {
    int row = c >> 3, cc = (c & 7) * 8;
    *(uint4*)&Ksh[row * KPAD + cc] = *(const uint4*)&qkv[baseK + (size_t)row * 1536 + cc];
  }
  __syncthreads();

  const int qt0 = q0 + wave * 16;
  const size_t baseQ = ((size_t)(b * TT + qt0 + l15)) * 1536 + h * 64;
  const bf16x8 aq0 = *(const bf16x8*)&qkv[baseQ + quad * 8];
  const bf16x8 aq1 = *(const bf16x8*)&qkv[baseQ + 32 + quad * 8];

  const __hip_bfloat16* V0 = VT + (size_t)(h * 64 + l15) * 4096 + (size_t)b * 2048 + j0;

  f32x4 o0 = {}, o1 = {}, o2 = {}, o3 = {};
  float lsum[4] = {0.f, 0.f, 0.f, 0.f};

  const int klo = (qt0 > (WWIN - 1)) ? (qt0 - (WWIN - 1)) : 0;
  const int c_lo = (klo - j0) >> 5;
  const int c_hi = (qt0 + 15 - j0) >> 5;
  __hip_bfloat16* Pw = &Psh[wave * 16 * PPAD];

  for (int c = c_lo; c <= c_hi; ++c) {
    const int krel = c * 32;
    bf16x8 bk00 = *(const bf16x8*)&Ksh[(krel + l15) * KPAD + quad * 8];
    bf16x8 bk01 = *(const bf16x8*)&Ksh[(krel + l15) * KPAD + 32 + quad * 8];
    bf16x8 bk10 = *(const bf16x8*)&Ksh[(krel + 16 + l15) * KPAD + quad * 8];
    bf16x8 bk11 = *(const bf16x8*)&Ksh[(krel + 16 + l15) * KPAD + 32 + quad * 8];
    f32x4 z = {};
    f32x4 s0 = __builtin_amdgcn_mfma_f32_16x16x32_bf16(aq0, bk00, z, 0, 0, 0);
    s0 = __builtin_amdgcn_mfma_f32_16x16x32_bf16(aq1, bk01, s0, 0, 0, 0);
    f32x4 s1 = __builtin_amdgcn_mfma_f32_16x16x32_bf16(aq0, bk10, z, 0, 0, 0);
    s1 = __builtin_amdgcn_mfma_f32_16x16x32_bf16(aq1, bk11, s1, 0, 0, 0);

    const int jj0 = j0 + krel + l15;
    const int jj1 = jj0 + 16;
#pragma unroll
    for (int r = 0; r < 4; ++r) {
      const int qrow = qt0 + quad * 4 + r;
      const bool ok0 = (jj0 <= qrow) && ((qrow - jj0) < WWIN);
      const bool ok1 = (jj1 <= qrow) && ((qrow - jj1) < WWIN);
      const float p0 = ok0 ? __expf(s0[r] * 0.125f) : 0.f;
      const float p1 = ok1 ? __expf(s1[r] * 0.125f) : 0.f;
      lsum[r] += p0 + p1;
      const int qloc = quad * 4 + r;
      Pw[qloc * PPAD + l15]      = __float2bfloat16(p0);
      Pw[qloc * PPAD + 16 + l15] = __float2bfloat16(p1);
    }
    asm volatile("s_waitcnt lgkmcnt(0)" ::: "memory");
    __builtin_amdgcn_wave_barrier();
    const bf16x8 pa = *(const bf16x8*)&Pw[l15 * PPAD + quad * 8];

    const int kgl = krel + quad * 8;
#pragma unroll
    for (int t = 0; t < 4; ++t) {
      const bf16x8 bv = *(const bf16x8*)&V0[(size_t)t * 65536 + kgl];
      if (t == 0)      o0 = __builtin_amdgcn_mfma_f32_16x16x32_bf16(pa, bv, o0, 0, 0, 0);
      else if (t == 1) o1 = __builtin_amdgcn_mfma_f32_16x16x32_bf16(pa, bv, o1, 0, 0, 0);
      else if (t == 2) o2 = __builtin_amdgcn_mfma_f32_16x16x32_bf16(pa, bv, o2, 0, 0, 0);
      else             o3 = __builtin_amdgcn_mfma_f32_16x16x32_bf16(pa, bv, o3, 0, 0, 0);
    }
    __builtin_amdgcn_wave_barrier();
  }

#pragma unroll
  for (int r = 0; r < 4; ++r) {
#pragma unroll
    for (int off = 8; off; off >>= 1) lsum[r] += __shfl_xor(lsum[r], off, 16);
  }

#pragma unroll
  for (int r = 0; r < 4; ++r) {
    const float inv = 1.f / lsum[r];
    const size_t ob = ((size_t)(b * TT + qt0 + quad * 4 + r)) * DD + h * 64 + l15;
    ao[ob]      = __float2bfloat16(o0[r] * inv);
    ao[ob + 16] = __float2bfloat16(o1[r] * inv);
    ao[ob + 32] = __float2bfloat16(o2[r] * inv);
    ao[ob + 48] = __float2bfloat16(o3[r] * inv);
  }
}

// ========================= cooperative mega-kernel =========================
struct MegaArgs {
  const float *tokens, *bq, *bk, *bv, *bo, *b1, *b2, *g1, *be1, *g2, *be2, *gf, *bf;
  const float *Wq, *Wk, *Wv, *Wo, *W1, *W2;
  float* outF;
  __hip_bfloat16 *xnao, *qkv, *hbuf, *VT, *wqkvT, *woT, *w1T, *w2T;
  float* bqkvc;
};

// GEMM phase (grid-strided tiles). Same math/layout as gemm_bt; full-K only.
template <int EPI, bool ROPE, int BM, int BN>
__device__ void gemm_phase(void* smemv, int bid, int tid,
                           const __hip_bfloat16* __restrict__ A,
                           const __hip_bfloat16* __restrict__ BT,
                           const float* __restrict__ bias,
                           __hip_bfloat16* __restrict__ Obf,
                           float* __restrict__ Of,
                           const float* __restrict__ Orin,
                           __hip_bfloat16* __restrict__ VTo,
                           int tilesN, int ntiles, int K, int ostride) {
  constexpr int MI = 2;
  constexpr int NJ = (BM == 64) ? 2 : 4;
  __hip_bfloat16* Ash = (__hip_bfloat16*)smemv;       // [4][BM*32]
  __hip_bfloat16* Bsh = Ash + 4 * BM * 32;            // [4][BN*32]
  const int wave = tid >> 6, lane = tid & 63;
  const int l15 = lane & 15, quad = lane >> 4;
  const int wm = (BM == 64) ? ((wave >> 1) * 32) : (wave * 32);
  const int wn = (BM == 64) ? ((wave & 1) * 32) : 0;
  const int r0 = tid >> 2, o0 = (tid & 3) * 8;

  for (int t = bid; t < ntiles; t += NB) {
    const int n0 = (t % tilesN) * BN;
    const int m0 = (t / tilesN) * BM;
    const __hip_bfloat16* Ap0 = A + (size_t)(m0 + r0) * K + o0;
    const __hip_bfloat16* Ap1 = Ap0 + (size_t)64 * K;
    const __hip_bfloat16* Bp0 = BT + (size_t)(n0 + r0) * K + o0;
    f32x4 acc[MI][NJ] = {};

    auto stage64 = [&](int buf, int k) {
      lds_load16(Ap0 + k,      Ash + (buf * 2 + 0) * BM * 32 + wave * 512);
      lds_load16(Ap0 + k + 32, Ash + (buf * 2 + 1) * BM * 32 + wave * 512);
      if constexpr (BM == 128) {
        lds_load16(Ap1 + k,      Ash + (buf * 2 + 0) * BM * 32 + 2048 + wave * 512);
        lds_load16(Ap1 + k + 32, Ash + (buf * 2 + 1) * BM * 32 + 2048 + wave * 512);
      }
      lds_load16(Bp0 + k,      Bsh + (buf * 2 + 0) * BN * 32 + wave * 512);
      lds_load16(Bp0 + k + 32, Bsh + (buf * 2 + 1) * BN * 32 + wave * 512);
    };
    auto cmp32 = [&](int idx) {
      const __hip_bfloat16* As = Ash + idx * BM * 32;
      const __hip_bfloat16* Bs = Bsh + idx * BN * 32;
      bf16x8 af[MI], bfr[NJ];
#pragma unroll
      for (int i = 0; i < MI; ++i)
        af[i] = *(const bf16x8*)&As[(wm + i * 16 + l15) * 32 + quad * 8];
#pragma unroll
      for (int j = 0; j < NJ; ++j)
        bfr[j] = *(const bf16x8*)&Bs[(wn + j * 16 + l15) * 32 + quad * 8];
#pragma unroll
      for (int i = 0; i < MI; ++i)
#pragma unroll
        for (int j = 0; j < NJ; ++j)
          acc[i][j] = __builtin_amdgcn_mfma_f32_16x16x32_bf16(af[i], bfr[j], acc[i][j], 0, 0, 0);
    };

    stage64(0, 0);
    for (int k0 = 0; k0 < K; k0 += 128) {
      __syncthreads();
      if (k0 + 64 < K) stage64(1, k0 + 64);
      cmp32(0); cmp32(1);
      __syncthreads();
      if (k0 + 128 < K) stage64(0, k0 + 128);
      cmp32(2); cmp32(3);
    }

    if constexpr (ROPE) {
      if (n0 < 1024) {
#pragma unroll
        for (int j = 0; j < 2; ++j) {
          const int col = n0 + wn + j * 16 + l15;
          const float bv0 = bias[col], bv1 = bias[col + 32];
          const float freq = __powf(10000.f, -(float)(j * 16 + l15) * (1.f / 32.f));
#pragma unroll
          for (int i = 0; i < MI; ++i) {
            const int row = m0 + wm + i * 16 + quad * 4;
#pragma unroll
            for (int r = 0; r < 4; ++r) {
              const int tt = (row + r) & 2047;
              float sn, cs;
              __sincosf((float)tt * freq, &sn, &cs);
              const float a0 = acc[i][j][r] + bv0;
              const float a1 = acc[i][j + 2][r] + bv1;
              const size_t idx = (size_t)(row + r) * ostride + col;
              Obf[idx]      = __float2bfloat16(a0 * cs - a1 * sn);
              Obf[idx + 32] = __float2bfloat16(a1 * cs + a0 * sn);
            }
          }
        }
      } else {
#pragma unroll
        for (int j = 0; j < NJ; ++j) {
          const int col = n0 + wn + j * 16 + l15;
          const float bv = bias[col];
          const int d = col - 1024;
#pragma unroll
          for (int i = 0; i < MI; ++i) {
            const int row = m0 + wm + i * 16 + quad * 4;
#pragma unroll
            for (int r = 0; r < 4; ++r)
              VTo[(size_t)d * 4096 + row + r] = __float2bfloat16(acc[i][j][r] + bv);
          }
        }
      }
    } else {
#pragma unroll
      for (int j = 0; j < NJ; ++j) {
        const int col = n0 + wn + j * 16 + l15;
        const float bv = bias[col];
#pragma unroll
        for (int i = 0; i < MI; ++i) {
          const int row = m0 + wm + i * 16 + quad * 4;
#pragma unroll
          for (int r = 0; r < 4; ++r) {
            float v = acc[i][j][r] + bv;
            size_t idx = (size_t)(row + r) * ostride + col;
            if (EPI == EPI_BF16) {
              Obf[idx] = __float2bfloat16(v);
            } else if (EPI == EPI_GELU) {
              float ge = 0.5f * v * (1.f + erff(v * 0.70710678118654752f));
              Obf[idx] = __float2bfloat16(ge);
            } else {  // EPI_RES
              Of[idx] = Orin[idx] + v;
            }
          }
        }
      }
    }
  }
}

__device__ void ln_phase(int bid, int tid, const float* __restrict__ x,
                         const float* __restrict__ g, const float* __restrict__ be,
                         __hip_bfloat16* __restrict__ out) {
  const int wave = tid >> 6, lane = tid & 63;
  for (int u = bid; u < 1024; u += NB) {
    const int row = u * 4 + wave;
    const float* xr = x + (size_t)row * DD;
    float v[8];
    float s = 0.f;
#pragma unroll
    for (int i = 0; i < 8; ++i) { v[i] = xr[lane + i * 64]; s += v[i]; }
#pragma unroll
    for (int off = 32; off; off >>= 1) s += __shfl_xor(s, off);
    float mu = s * (1.f / DD);
    float qs = 0.f;
#pragma unroll
    for (int i = 0; i < 8; ++i) { float d = v[i] - mu; qs += d * d; }
#pragma unroll
    for (int off = 32; off; off >>= 1) qs += __shfl_xor(qs, off);
    float rstd = rsqrtf(qs * (1.f / DD) + 1e-5f);
#pragma unroll
    for (int i = 0; i < 8; ++i) {
      int c = lane + i * 64;
      out[(size_t)row * DD + c] = __float2bfloat16((v[i] - mu) * rstd * g[c] + be[c]);
    }
  }
}

__device__ void lnf_phase(int bid, int tid, const float* __restrict__ x,
                          const float* __restrict__ g, const float* __restrict__ be,
                          float* __restrict__ out) {
  const int wave = tid >> 6, lane = tid & 63;
  for (int u = bid; u < 1024; u += NB) {
    const int row = u * 4 + wave;
    const float* xr = x + (size_t)row * DD;
    float v[8];
    float s = 0.f;
#pragma unroll
    for (int i = 0; i < 8; ++i) { v[i] = xr[lane + i * 64]; s += v[i]; }
#pragma unroll
    for (int off = 32; off; off >>= 1) s += __shfl_xor(s, off);
    float mu = s * (1.f / DD);
    float qs = 0.f;
#pragma unroll
    for (int i = 0; i < 8; ++i) { float d = v[i] - mu; qs += d * d; }
#pragma unroll
    for (int off = 32; off; off >>= 1) qs += __shfl_xor(qs, off);
    float rstd = rsqrtf(qs * (1.f / DD) + 1e-5f);
#pragma unroll
    for (int i = 0; i < 8; ++i) {
      int c = lane + i * 64;
      out[(size_t)row * DD + c] = (v[i] - mu) * rstd * g[c] + be[c];
    }
  }
}

__global__ __launch_bounds__(256, 3) void mega(MegaArgs a) {
  cooperative_groups::grid_group grid = cooperative_groups::this_grid();
  __shared__ __align__(16) char smem[51200];
  const int tid = threadIdx.x;
  const int bid = blockIdx.x;
  const int wave = tid >> 6, lane = tid & 63;
  const int l15 = lane & 15, quad = lane >> 4;

  // ---- phase 0: weight transposes + qkv bias concat + initial LN ----
  {
    float (*tile)[33] = (float(*)[33])smem;
    for (int u = bid; u < 4 * 3078 + 1024; u += NB) {
      if (u >= 4 * 3078) {
        // initial LN unit (reads tokens, writes xn)
        const int row = (u - 4 * 3078) * 4 + wave;
        const float* xr = a.tokens + (size_t)row * DD;
        float v[8];
        float s = 0.f;
#pragma unroll
        for (int i = 0; i < 8; ++i) { v[i] = xr[lane + i * 64]; s += v[i]; }
#pragma unroll
        for (int off = 32; off; off >>= 1) s += __shfl_xor(s, off);
        float mu = s * (1.f / DD);
        float qs = 0.f;
#pragma unroll
        for (int i = 0; i < 8; ++i) { float d = v[i] - mu; qs += d * d; }
#pragma unroll
        for (int off = 32; off; off >>= 1) qs += __shfl_xor(qs, off);
        float rstd = rsqrtf(qs * (1.f / DD) + 1e-5f);
#pragma unroll
        for (int i = 0; i < 8; ++i) {
          int c = lane + i * 64;
          a.xnao[(size_t)row * DD + c] =
              __float2bfloat16((v[i] - mu) * rstd * a.g1[c] + a.be1[c]);
        }
        continue;
      }
      const int l = u / 3078, b = u % 3078;
      if (b >= 3072) {
        int n = (b - 3072) * 256 + tid;
        if (n < 1536) {
          float v;
          if (n < 512)       v = a.bq[l * 512 + n];
          else if (n < 1024) v = a.bk[l * 512 + n - 512];
          else               v = a.bv[l * 512 + n - 1024];
          a.bqkvc[l * 1536 + n] = v;
        }
        continue;
      }
      const float* src;
      __hip_bfloat16* dst;
      int K, N, t;
      if (b < 768) {
        int which = b >> 8; t = b & 255;
        src = ((which == 0) ? a.Wq : (which == 1) ? a.Wk : a.Wv) + (size_t)l * 262144;
        dst = a.wqkvT + (size_t)l * 786432 + which * 262144;
        K = 512; N = 512;
      } else if (b < 1024) {
        t = b - 768;  src = a.Wo + (size_t)l * 262144;  dst = a.woT + (size_t)l * 262144;  K = 512; N = 512;
      } else if (b < 2048) {
        t = b - 1024; src = a.W1 + (size_t)l * 1048576; dst = a.w1T + (size_t)l * 1048576; K = 512; N = 2048;
      } else {
        t = b - 2048; src = a.W2 + (size_t)l * 1048576; dst = a.w2T + (size_t)l * 1048576; K = 2048; N = 512;
      }
      const int tilesN = N >> 5;
      const int n0 = (t % tilesN) * 32, k0 = (t / tilesN) * 32;
      const int tx = tid & 31, ty = tid >> 5;
      __syncthreads();   // guard tile reuse across units
#pragma unroll
      for (int r = 0; r < 32; r += 8)
        tile[ty + r][tx] = src[(size_t)(k0 + ty + r) * N + n0 + tx];
      __syncthreads();
#pragma unroll
      for (int r = 0; r < 32; r += 8)
        dst[(size_t)(n0 + ty + r) * K + k0 + tx] = __float2bfloat16(tile[tx][ty + r]);
    }
  }
  grid.sync();

  float* x = a.outF;
  for (int l = 0; l < LL; ++l) {
    const __hip_bfloat16* qkvT_l = a.wqkvT + (size_t)l * 786432;
    const __hip_bfloat16* woT_l  = a.woT   + (size_t)l * 262144;
    const __hip_bfloat16* w1T_l  = a.w1T   + (size_t)l * 1048576;
    const __hip_bfloat16* w2T_l  = a.w2T   + (size_t)l * 1048576;

    // QKV + RoPE + VT  (128x64, tiles 24x32 = 768)
    gemm_phase<EPI_BF16, true, 128, 64>(smem, bid, tid, a.xnao, qkvT_l,
                                        a.bqkvc + l * 1536, a.qkv, nullptr, nullptr,
                                        a.VT, 24, 768, 512, 1536);
    grid.sync();

    // attention (units 512 = 32 qblocks x 16 bh)
    {
      __hip_bfloat16* Ksh = (__hip_bfloat16*)smem;       // 320*72
      __hip_bfloat16* Psh = Ksh + 320 * 72;              // 4*16*40
      for (int u = bid; u < 512; u += NB) {
        const int qb = u & 31, bh = u >> 5;
        const int bb = bh >> 3, h = bh & 7;
        const int q0 = qb * 64;
        const int j0 = (q0 >= WWIN) ? (q0 - WWIN) : 0;
        const int nk = (q0 + 63) - j0 + 1;

        __syncthreads();   // guard Ksh reuse across units
        const size_t baseK = ((size_t)(bb * TT + j0)) * 1536 + 512 + h * 64;
        for (int c = tid; c < nk * 8; c += 256) {
          int row = c >> 3, cc = (c & 7) * 8;
          *(uint4*)&Ksh[row * 72 + cc] = *(const uint4*)&a.qkv[baseK + (size_t)row * 1536 + cc];
        }
        __syncthreads();

        const int qt0 = q0 + wave * 16;
        const size_t baseQ = ((size_t)(bb * TT + qt0 + l15)) * 1536 + h * 64;
        const bf16x8 aq0 = *(const bf16x8*)&a.qkv[baseQ + quad * 8];
        const bf16x8 aq1 = *(const bf16x8*)&a.qkv[baseQ + 32 + quad * 8];
        const __hip_bfloat16* V0 = a.VT + (size_t)(h * 64 + l15) * 4096 + (size_t)bb * 2048 + j0;

        f32x4 o0 = {}, o1 = {}, o2 = {}, o3 = {};
        float lsum[4] = {0.f, 0.f, 0.f, 0.f};
        const int klo = (qt0 > (WWIN - 1)) ? (qt0 - (WWIN - 1)) : 0;
        const int c_lo = (klo - j0) >> 5;
        const int c_hi = (qt0 + 15 - j0) >> 5;
        __hip_bfloat16* Pw = &Psh[wave * 16 * 40];

        for (int c = c_lo; c <= c_hi; ++c) {
          const int krel = c * 32;
          bf16x8 bk00 = *(const bf16x8*)&Ksh[(krel + l15) * 72 + quad * 8];
          bf16x8 bk01 = *(const bf16x8*)&Ksh[(krel + l15) * 72 + 32 + quad * 8];
          bf16x8 bk10 = *(const bf16x8*)&Ksh[(krel + 16 + l15) * 72 + quad * 8];
          bf16x8 bk11 = *(const bf16x8*)&Ksh[(krel + 16 + l15) * 72 + 32 + quad * 8];
          f32x4 z = {};
          f32x4 s0 = __builtin_amdgcn_mfma_f32_16x16x32_bf16(aq0, bk00, z, 0, 0, 0);
          s0 = __builtin_amdgcn_mfma_f32_16x16x32_bf16(aq1, bk01, s0, 0, 0, 0);
          f32x4 s1 = __builtin_amdgcn_mfma_f32_16x16x32_bf16(aq0, bk10, z, 0, 0, 0);
          s1 = __builtin_amdgcn_mfma_f32_16x16x32_bf16(aq1, bk11, s1, 0, 0, 0);

          const int jj0 = j0 + krel + l15;
          const int jj1 = jj0 + 16;
#pragma unroll
          for (int r = 0; r < 4; ++r) {
            const int qrow = qt0 + quad * 4 + r;
            const bool ok0 = (jj0 <= qrow) && ((qrow - jj0) < WWIN);
            const bool ok1 = (jj1 <= qrow) && ((qrow - jj1) < WWIN);
            const float p0 = ok0 ? __expf(s0[r] * 0.125f) : 0.f;
            const float p1 = ok1 ? __expf(s1[r] * 0.125f) : 0.f;
            lsum[r] += p0 + p1;
            const int qloc = quad * 4 + r;
            Pw[qloc * 40 + l15]      = __float2bfloat16(p0);
            Pw[qloc * 40 + 16 + l15] = __float2bfloat16(p1);
          }
          asm volatile("s_waitcnt lgkmcnt(0)" ::: "memory");
          __builtin_amdgcn_wave_barrier();
          const bf16x8 pa = *(const bf16x8*)&Pw[l15 * 40 + quad * 8];

          const int kgl = krel + quad * 8;
#pragma unroll
          for (int t = 0; t < 4; ++t) {
            const bf16x8 bv = *(const bf16x8*)&V0[(size_t)t * 65536 + kgl];
            if (t == 0)      o0 = __builtin_amdgcn_mfma_f32_16x16x32_bf16(pa, bv, o0, 0, 0, 0);
            else if (t == 1) o1 = __builtin_amdgcn_mfma_f32_16x16x32_bf16(pa, bv, o1, 0, 0, 0);
            else if (t == 2) o2 = __builtin_amdgcn_mfma_f32_16x16x32_bf16(pa, bv, o2, 0, 0, 0);
            else             o3 = __builtin_amdgcn_mfma_f32_16x16x32_bf16(pa, bv, o3, 0, 0, 0);
          }
          __builtin_amdgcn_wave_barrier();
        }

#pragma unroll
        for (int r = 0; r < 4; ++r) {
#pragma unroll
          for (int off = 8; off; off >>= 1) lsum[r] += __shfl_xor(lsum[r], off, 16);
        }
#pragma unroll
        for (int r = 0; r < 4; ++r) {
          const float inv = 1.f / lsum[r];
          const size_t ob = ((size_t)(bb * TT + qt0 + quad * 4 + r)) * DD + h * 64 + l15;
          a.xnao[ob]      = __float2bfloat16(o0[r] * inv);
          a.xnao[ob + 16] = __float2bfloat16(o1[r] * inv);
          a.xnao[ob + 32] = __float2bfloat16(o2[r] * inv);
          a.xnao[ob + 48] = __float2bfloat16(o3[r] * inv);
        }
      }
    }
    grid.sync();

    // Wo + residual  (64x64, tiles 8x64 = 512)
    gemm_phase<EPI_RES, false, 64, 64>(smem, bid, tid, a.xnao, woT_l,
                                       a.bo + l * 512, nullptr, x,
                                       (l == 0) ? a.tokens : x, nullptr,
                                       8, 512, 512, 512);
    grid.sync();

    // LN2
    ln_phase(bid, tid, x, a.g2 + l * 512, a.be2 + l * 512, a.xnao);
    grid.sync();

    // FFN1 + GELU  (128x64, tiles 32x32 = 1024)
    gemm_phase<EPI_GELU, false, 128, 64>(smem, bid, tid, a.xnao, w1T_l,
                                         a.b1 + l * 2048, a.hbuf, nullptr, nullptr,
                                         nullptr, 32, 1024, 512, 2048);
    grid.sync();

    // FFN2 + residual  (64x64, K=2048, tiles 8x64 = 512)
    gemm_phase<EPI_RES, false, 64, 64>(smem, bid, tid, a.hbuf, w2T_l,
                                       a.b2 + l * 512, nullptr, x, x, nullptr,
                                       8, 512, 2048, 512);
    grid.sync();

    // LN1 of next layer, or final LN
    if (l < LL - 1)
      ln_phase(bid, tid, x, a.g1 + (l + 1) * 512, a.be1 + (l + 1) * 512, a.xnao);
    else
      lnf_phase(bid, tid, x, a.gf, a.bf, a.outF);
    grid.sync();
  }
}

// ---------- host launch ----------
extern "C" void kernel_launch(void* const* d_in, const int* in_sizes, int n_in,
                              void* d_out, int out_size, void* d_ws, size_t ws_size,
                              hipStream_t stream) {
  float* outF = (float*)d_out;

  int code = 0;
  if (n_in != 19)                      code = 1;
  else if (in_sizes[0]  != 2097152)    code = 2;
  else if (in_sizes[1]  != 1048576)    code = 3;
  else if (in_sizes[9]  != 4194304)    code = 4;
  else if (in_sizes[17] != 512)        code = 5;
  if (code != 0 || ws_size < 27287552ull) {
    float C = code ? (150.f + 15.f * (float)code) : (1000.f + (float)(ws_size >> 20));
    fill_const<<<8192, 256, 0, stream>>>(outF, C, NOUT);
    return;
  }

  const float* tokens = (const float*)d_in[0];
  const float* Wq  = (const float*)d_in[1];
  const float* Wk  = (const float*)d_in[2];
  const float* Wv  = (const float*)d_in[3];
  const float* Wo  = (const float*)d_in[4];
  const float* bq  = (const float*)d_in[5];
  const float* bk  = (const float*)d_in[6];
  const float* bv  = (const float*)d_in[7];
  const float* bo  = (const float*)d_in[8];
  const float* W1  = (const float*)d_in[9];
  const float* b1  = (const float*)d_in[10];
  const float* W2  = (const float*)d_in[11];
  const float* b2  = (const float*)d_in[12];
  const float* g1  = (const float*)d_in[13];
  const float* be1 = (const float*)d_in[14];
  const float* g2  = (const float*)d_in[15];
  const float* be2 = (const float*)d_in[16];
  const float* gf  = (const float*)d_in[17];
  const float* bf  = (const float*)d_in[18];

  char* ws = (char*)d_ws;
  __hip_bfloat16* xnao  = (__hip_bfloat16*)(ws + 0);
  __hip_bfloat16* qkv   = (__hip_bfloat16*)(ws + 4194304);
  __hip_bfloat16* hbuf  = (__hip_bfloat16*)(ws + 4194304);
  __hip_bfloat16* VT    = (__hip_bfloat16*)(ws + 16777216);

  const bool big = ws_size >= 46161920ull;
  __hip_bfloat16 *wqkvT, *woT, *w1T, *w2T;
  float* bqkvc;
  if (big) {
    wqkvT = (__hip_bfloat16*)(ws + 20971520);
    woT   = (__hip_bfloat16*)(ws + 27262976);
    w1T   = (__hip_bfloat16*)(ws + 29360128);
    w2T   = (__hip_bfloat16*)(ws + 37748736);
    bqkvc = (float*)(ws + 46137344);
  } else {
    wqkvT = (__hip_bfloat16*)(ws + 20971520);
    woT   = (__hip_bfloat16*)(ws + 22544384);
    w1T   = (__hip_bfloat16*)(ws + 23068672);
    w2T   = (__hip_bfloat16*)(ws + 25165824);
    bqkvc = (float*)(ws + 27262976);
  }
  __hip_bfloat16* xn = xnao;
  __hip_bfloat16* ao = xnao;
  float* x = outF;

  if (big) {
    // ---- preferred: single cooperative mega-kernel ----
    MegaArgs ma;
    ma.tokens = tokens; ma.bq = bq; ma.bk = bk; ma.bv = bv; ma.bo = bo;
    ma.b1 = b1; ma.b2 = b2; ma.g1 = g1; ma.be1 = be1; ma.g2 = g2; ma.be2 = be2;
    ma.gf = gf; ma.bf = bf;
    ma.Wq = Wq; ma.Wk = Wk; ma.Wv = Wv; ma.Wo = Wo; ma.W1 = W1; ma.W2 = W2;
    ma.outF = outF;
    ma.xnao = xnao; ma.qkv = qkv; ma.hbuf = hbuf; ma.VT = VT;
    ma.wqkvT = wqkvT; ma.woT = woT; ma.w1T = w1T; ma.w2T = w2T;
    ma.bqkvc = bqkvc;
    void* kargs[] = {(void*)&ma};
    if (hipLaunchCooperativeKernel(reinterpret_cast<void*>(mega), dim3(NB), dim3(256),
                                   kargs, 0, stream) == hipSuccess)
      return;
    // cooperative launch unavailable -> fall through to multi-kernel flow

    transpose_all<<<dim3(3078, 4), 256, 0, stream>>>(Wq, Wk, Wv, Wo, W1, W2,
                                                     wqkvT, woT, w1T, w2T,
                                                     bq, bk, bv, bqkvc);
    ln_kernel<<<1024, 256, 0, stream>>>(tokens, g1, be1, xn);
    for (int l = 0; l < LL; ++l) {
      __hip_bfloat16* qkvT_l = wqkvT + (size_t)l * 786432;
      __hip_bfloat16* woT_l  = woT   + (size_t)l * 262144;
      __hip_bfloat16* w1T_l  = w1T   + (size_t)l * 1048576;
      __hip_bfloat16* w2T_l  = w2T   + (size_t)l * 1048576;

      gemm_bt<EPI_BF16, true, 128, 64><<<dim3(24, 32), 256, 0, stream>>>(
          xn, qkvT_l, bqkvc + l * 1536, qkv, nullptr, nullptr, VT,
          MM, 1536, 512, 512, 1536, 0);
      attn_mfma<<<dim3(32, 16), 256, 0, stream>>>(qkv, VT, ao);
      gemm_bt<EPI_RES, false, 64, 64><<<dim3(8, 64), 256, 0, stream>>>(
          ao, woT_l, bo + l * 512, nullptr, x, (l == 0) ? tokens : x, nullptr,
          MM, 512, 512, 512, 512, 0);
      ln_kernel<<<1024, 256, 0, stream>>>(x, g2 + l * 512, be2 + l * 512, xn);
      gemm_bt<EPI_GELU, false, 128, 128><<<dim3(16, 32), 256, 0, stream>>>(
          xn, w1T_l, b1 + l * 2048, hbuf, nullptr, nullptr, nullptr,
          MM, 2048, 512, 512, 2048, 0);
      gemm_bt<EPI_RES, false, 64, 64><<<dim3(8, 64), 256, 0, stream>>>(
          hbuf, w2T_l, b2 + l * 512, nullptr, x, x, nullptr,
          MM, 512, 2048, 2048, 512, 0);
      if (l < LL - 1)
        ln_kernel<<<1024, 256, 0, stream>>>(x, g1 + (l + 1) * 512,
                                            be1 + (l + 1) * 512, xn);
      else
        ln_f32out<<<1024, 256, 0, stream>>>(x, gf, bf, outF);
    }
    return;
  }

  // ---- small-ws fallback: per-layer transposes, atomic split-K ----
  prep<<<8216, 256, 0, stream>>>(tokens, x, bq, bk, bv, bqkvc);

  for (int l = 0; l < LL; ++l) {
    transpose_all<<<dim3(3072, 1), 256, 0, stream>>>(
        Wq + (size_t)l * 262144, Wk + (size_t)l * 262144, Wv + (size_t)l * 262144,
        Wo + (size_t)l * 262144, W1 + (size_t)l * 1048576, W2 + (size_t)l * 1048576,
        wqkvT, woT, w1T, w2T, bq, bk, bv, bqkvc);

    ln_kernel<<<1024, 256, 0, stream>>>(x, g1 + l * 512, be1 + l * 512, xn);
    gemm_bt<EPI_BF16, true, 128, 64><<<dim3(24, 32), 256, 0, stream>>>(
        xn, wqkvT, bqkvc + l * 1536, qkv, nullptr, nullptr, VT,
        MM, 1536, 512, 512, 1536, 0);
    attn_mfma<<<dim3(32, 16), 256, 0, stream>>>(qkv, VT, ao);
    gemm_bt<EPI_ADDF32, false, 128, 64><<<dim3(8, 32, 2), 256, 0, stream>>>(
        ao, woT, bo + l * 512, nullptr, x, nullptr, nullptr,
        MM, 512, 512, 256, 512, 0);
    ln_kernel<<<1024, 256, 0, stream>>>(x, g2 + l * 512, be2 + l * 512, xn);
    gemm_bt<EPI_GELU, false, 128, 128><<<dim3(16, 32), 256, 0, stream>>>(
        xn, w1T, b1 + l * 2048, hbuf, nullptr, nullptr, nullptr,
        MM, 2048, 512, 512, 2048, 0);
    gemm_bt<EPI_ADDF32, false, 128, 128><<<dim3(4, 32, 4), 256, 0, stream>>>(
        hbuf, w2T, b2 + l * 512, nullptr, x, nullptr, nullptr,
        MM, 512, 2048, 512, 512, 0);
  }
  ln_f32out<<<1024, 256, 0, stream>>>(x, gf, bf, outF);
}

// Round 7
// 485.738 us; speedup vs baseline: 6.2920x; 6.2920x over previous
//
#include <hip/hip_runtime.h>
#include <hip/hip_bf16.h>

#define BQ 2
#define TT 2048
#define DD 512
#define HH 8
#define LL 4
#define DFFN 2048
#define WWIN 256
#define DHD 64
#define MM (BQ*TT)   // 4096 token rows
#define NOUT (MM*DD)

typedef __attribute__((ext_vector_type(8))) short bf16x8;
typedef __attribute__((ext_vector_type(4))) float f32x4;

// ---------- helpers ----------
__device__ __forceinline__ void lds_load16(const void* g, void* l) {
  __builtin_amdgcn_global_load_lds((const __attribute__((address_space(1))) void*)g,
                                   (__attribute__((address_space(3))) void*)l,
                                   16, 0, 0);
}

// Bijective XCD-chunk swizzle (T1, m204): orig%8 = XCD under round-robin
// dispatch; give each XCD a CONTIGUOUS tile range so blocks sharing A/h rows
// hit the same per-XCD L2. Requires nwg % 8 == 0 (all our grids comply).
__device__ __forceinline__ void xcd_remap(int& bx, int& by) {
  const int nwg = gridDim.x * gridDim.y;
  if ((nwg & 7) == 0) {
    const int orig = blockIdx.x + gridDim.x * blockIdx.y;
    const int id = (orig & 7) * (nwg >> 3) + (orig >> 3);
    bx = id % gridDim.x;
    by = id / gridDim.x;
  } else {
    bx = blockIdx.x;
    by = blockIdx.y;
  }
}

// ---------- diagnostic fill ----------
__global__ __launch_bounds__(256) void fill_const(float* __restrict__ out, float C, int n) {
  int i = blockIdx.x * 256 + threadIdx.x;
  if (i < n) out[i] = C;
}

// ---------- legacy prep: tokens -> x copy + qkv bias concat (fallback flow) ----------
__global__ __launch_bounds__(256) void prep(const float* __restrict__ tokens,
                                            float* __restrict__ x,
                                            const float* __restrict__ bq,
                                            const float* __restrict__ bk,
                                            const float* __restrict__ bv,
                                            float* __restrict__ bqkvc) {
  const int b = blockIdx.x;
  if (b < 8192) {
    int i = b * 256 + threadIdx.x;
    x[i] = tokens[i];
  } else {
    int idx = (b - 8192) * 256 + threadIdx.x;
    if (idx < LL * 1536) {
      int l = idx / 1536, n = idx % 1536;
      float v;
      if (n < 512)       v = bq[l * 512 + n];
      else if (n < 1024) v = bk[l * 512 + n - 512];
      else               v = bv[l * 512 + n - 1024];
      bqkvc[idx] = v;
    }
  }
}

// ---------- weight transpose fp32(K,N)->bf16(N,K); + qkv bias concat blocks ----------
__global__ __launch_bounds__(256) void transpose_all(const float* __restrict__ Wq,
                                                     const float* __restrict__ Wk,
                                                     const float* __restrict__ Wv,
                                                     const float* __restrict__ Wo,
                                                     const float* __restrict__ W1,
                                                     const float* __restrict__ W2,
                                                     __hip_bfloat16* __restrict__ wqkvT,
                                                     __hip_bfloat16* __restrict__ woT,
                                                     __hip_bfloat16* __restrict__ w1T,
                                                     __hip_bfloat16* __restrict__ w2T,
                                                     const float* __restrict__ bq,
                                                     const float* __restrict__ bk,
                                                     const float* __restrict__ bv,
                                                     float* __restrict__ bqkvc) {
  const int l = blockIdx.y;
  const int b = blockIdx.x;
  if (b >= 3072) {
    int n = (b - 3072) * 256 + threadIdx.x;
    if (n < 1536) {
      float v;
      if (n < 512)       v = bq[l * 512 + n];
      else if (n < 1024) v = bk[l * 512 + n - 512];
      else               v = bv[l * 512 + n - 1024];
      bqkvc[l * 1536 + n] = v;
    }
    return;
  }
  __shared__ float tile[32][33];
  const float* src;
  __hip_bfloat16* dst;
  int K, N, t;
  if (b < 768) {
    int which = b >> 8; t = b & 255;
    src = ((which == 0) ? Wq : (which == 1) ? Wk : Wv) + (size_t)l * 262144;
    dst = wqkvT + (size_t)l * 786432 + which * 262144;
    K = 512; N = 512;
  } else if (b < 1024) {
    t = b - 768;  src = Wo + (size_t)l * 262144;  dst = woT + (size_t)l * 262144;  K = 512; N = 512;
  } else if (b < 2048) {
    t = b - 1024; src = W1 + (size_t)l * 1048576; dst = w1T + (size_t)l * 1048576; K = 512; N = 2048;
  } else {
    t = b - 2048; src = W2 + (size_t)l * 1048576; dst = w2T + (size_t)l * 1048576; K = 2048; N = 512;
  }
  const int tilesN = N >> 5;
  const int n0 = (t % tilesN) * 32, k0 = (t / tilesN) * 32;
  const int tx = threadIdx.x & 31, ty = threadIdx.x >> 5;
#pragma unroll
  for (int r = 0; r < 32; r += 8)
    tile[ty + r][tx] = src[(size_t)(k0 + ty + r) * N + n0 + tx];
  __syncthreads();
#pragma unroll
  for (int r = 0; r < 32; r += 8)
    dst[(size_t)(n0 + ty + r) * K + k0 + tx] = __float2bfloat16(tile[tx][ty + r]);
}

// ---------- LayerNorm: fp32 -> bf16 ----------
__global__ __launch_bounds__(256) void ln_kernel(const float* __restrict__ x,
                                                 const float* __restrict__ g,
                                                 const float* __restrict__ b,
                                                 __hip_bfloat16* __restrict__ out) {
  const int wave = threadIdx.x >> 6, lane = threadIdx.x & 63;
  const int row = blockIdx.x * 4 + wave;
  const float* xr = x + (size_t)row * DD;
  float v[8];
  float s = 0.f;
#pragma unroll
  for (int i = 0; i < 8; ++i) { v[i] = xr[lane + i * 64]; s += v[i]; }
#pragma unroll
  for (int off = 32; off; off >>= 1) s += __shfl_xor(s, off);
  float mu = s * (1.f / DD);
  float qs = 0.f;
#pragma unroll
  for (int i = 0; i < 8; ++i) { float d = v[i] - mu; qs += d * d; }
#pragma unroll
  for (int off = 32; off; off >>= 1) qs += __shfl_xor(qs, off);
  float rstd = rsqrtf(qs * (1.f / DD) + 1e-5f);
#pragma unroll
  for (int i = 0; i < 8; ++i) {
    int c = lane + i * 64;
    out[(size_t)row * DD + c] = __float2bfloat16((v[i] - mu) * rstd * g[c] + b[c]);
  }
}

// ---------- final LayerNorm: fp32 -> fp32 ----------
__global__ __launch_bounds__(256) void ln_f32out(const float* __restrict__ x,
                                                 const float* __restrict__ g,
                                                 const float* __restrict__ b,
                                                 float* __restrict__ out) {
  const int wave = threadIdx.x >> 6, lane = threadIdx.x & 63;
  const int row = blockIdx.x * 4 + wave;
  const float* xr = x + (size_t)row * DD;
  float v[8];
  float s = 0.f;
#pragma unroll
  for (int i = 0; i < 8; ++i) { v[i] = xr[lane + i * 64]; s += v[i]; }
#pragma unroll
  for (int off = 32; off; off >>= 1) s += __shfl_xor(s, off);
  float mu = s * (1.f / DD);
  float qs = 0.f;
#pragma unroll
  for (int i = 0; i < 8; ++i) { float d = v[i] - mu; qs += d * d; }
#pragma unroll
  for (int off = 32; off; off >>= 1) qs += __shfl_xor(qs, off);
  float rstd = rsqrtf(qs * (1.f / DD) + 1e-5f);
#pragma unroll
  for (int i = 0; i < 8; ++i) {
    int c = lane + i * 64;
    out[(size_t)row * DD + c] = (v[i] - mu) * rstd * g[c] + b[c];
  }
}

// ---------- MFMA GEMM: double-pumped BK=64, XCD-chunk swizzled ----------
enum { EPI_BF16 = 0, EPI_GELU = 1, EPI_ADDF32 = 2, EPI_RES = 3 };

template <int EPI, bool ROPE, int BM, int BN>
__global__ __launch_bounds__(256, 1) void gemm_bt(const __hip_bfloat16* __restrict__ A,
                                                  const __hip_bfloat16* __restrict__ BT,
                                                  const float* __restrict__ bias,
                                                  __hip_bfloat16* __restrict__ Obf,
                                                  float* __restrict__ Of,
                                                  const float* __restrict__ Orin,
                                                  __hip_bfloat16* __restrict__ VTo,
                                                  int M, int N, int K, int KS,
                                                  int ostride, int ooff) {
  constexpr int MI = (BM == 64) ? 2 : ((BN == 128) ? 4 : 2);
  constexpr int NJ = (BM == 64) ? 2 : 4;
  __shared__ __align__(16) __hip_bfloat16 Ash[2][2][BM * 32];
  __shared__ __align__(16) __hip_bfloat16 Bsh[2][2][BN * 32];
  const int tid = threadIdx.x;
  const int wave = tid >> 6;
  const int lane = tid & 63;
  int bx, by;
  xcd_remap(bx, by);
  const int m0 = by * BM;
  const int n0 = bx * BN;
  const int kbase = blockIdx.z * KS;
  const int wm = (BM == 64) ? ((wave >> 1) * 32)
                            : ((BN == 128) ? ((wave >> 1) * 64) : (wave * 32));
  const int wn = (BM == 64) ? ((wave & 1) * 32)
                            : ((BN == 128) ? ((wave & 1) * 64) : 0);
  const int l15 = lane & 15;
  const int quad = lane >> 4;

  f32x4 acc[MI][NJ] = {};

  const int r0 = tid >> 2;
  const int o0 = (tid & 3) * 8;

  const __hip_bfloat16* Ap0 = A + (size_t)(m0 + r0) * K + kbase + o0;
  const __hip_bfloat16* Ap1 = Ap0 + (size_t)64 * K;
  const __hip_bfloat16* Bp0 = BT + (size_t)(n0 + r0) * K + kbase + o0;
  const __hip_bfloat16* Bp1 = Bp0 + (size_t)64 * K;

  auto stage64 = [&](int buf, int k) {
    lds_load16(Ap0 + k,      &Ash[buf][0][wave * 512]);
    lds_load16(Ap0 + k + 32, &Ash[buf][1][wave * 512]);
    if constexpr (BM == 128) {
      lds_load16(Ap1 + k,      &Ash[buf][0][2048 + wave * 512]);
      lds_load16(Ap1 + k + 32, &Ash[buf][1][2048 + wave * 512]);
    }
    lds_load16(Bp0 + k,      &Bsh[buf][0][wave * 512]);
    lds_load16(Bp0 + k + 32, &Bsh[buf][1][wave * 512]);
    if constexpr (BN == 128) {
      lds_load16(Bp1 + k,      &Bsh[buf][0][2048 + wave * 512]);
      lds_load16(Bp1 + k + 32, &Bsh[buf][1][2048 + wave * 512]);
    }
  };
  auto compute = [&](const __hip_bfloat16* As, const __hip_bfloat16* Bs) {
    bf16x8 af[MI], bfr[NJ];
#pragma unroll
    for (int i = 0; i < MI; ++i)
      af[i] = *(const bf16x8*)&As[(wm + i * 16 + l15) * 32 + quad * 8];
#pragma unroll
    for (int j = 0; j < NJ; ++j)
      bfr[j] = *(const bf16x8*)&Bs[(wn + j * 16 + l15) * 32 + quad * 8];
#pragma unroll
    for (int i = 0; i < MI; ++i)
#pragma unroll
      for (int j = 0; j < NJ; ++j)
        acc[i][j] = __builtin_amdgcn_mfma_f32_16x16x32_bf16(af[i], bfr[j], acc[i][j], 0, 0, 0);
  };
  auto compute64 = [&](int buf) {
    compute(Ash[buf][0], Bsh[buf][0]);
    compute(Ash[buf][1], Bsh[buf][1]);
  };

  stage64(0, 0);
  for (int k0 = 0; k0 < KS; k0 += 128) {       // KS % 128 == 0
    __syncthreads();
    if (k0 + 64 < KS) stage64(1, k0 + 64);
    compute64(0);
    __syncthreads();
    if (k0 + 128 < KS) stage64(0, k0 + 128);
    compute64(1);
  }

  if constexpr (ROPE) {
    if (n0 < 1024) {
      // q/k sections: rotate (d, d+32) pairs; write to qkv row-major
#pragma unroll
      for (int j = 0; j < 2; ++j) {
        const int col = n0 + wn + j * 16 + l15;
        const float bv0 = bias[col], bv1 = bias[col + 32];
        const float freq = __powf(10000.f, -(float)(j * 16 + l15) * (1.f / 32.f));
#pragma unroll
        for (int i = 0; i < MI; ++i) {
          const int row = m0 + wm + i * 16 + quad * 4;
#pragma unroll
          for (int r = 0; r < 4; ++r) {
            const int t = (row + r) & 2047;
            float sn, cs;
            __sincosf((float)t * freq, &sn, &cs);
            const float a0 = acc[i][j][r] + bv0;
            const float a1 = acc[i][j + 2][r] + bv1;
            const size_t idx = (size_t)(row + r) * ostride + ooff + col;
            Obf[idx]      = __float2bfloat16(a0 * cs - a1 * sn);
            Obf[idx + 32] = __float2bfloat16(a1 * cs + a0 * sn);
          }
        }
      }
    } else {
      // V section: bias + store transposed VT[d][token]
#pragma unroll
      for (int j = 0; j < NJ; ++j) {
        const int col = n0 + wn + j * 16 + l15;
        const float bv = bias[col];
        const int d = col - 1024;
#pragma unroll
        for (int i = 0; i < MI; ++i) {
          const int row = m0 + wm + i * 16 + quad * 4;
#pragma unroll
          for (int r = 0; r < 4; ++r)
            VTo[(size_t)d * 4096 + row + r] = __float2bfloat16(acc[i][j][r] + bv);
        }
      }
    }
    return;
  }

#pragma unroll
  for (int j = 0; j < NJ; ++j) {
    const int col = n0 + wn + j * 16 + l15;
    const float bv = (EPI == EPI_RES || blockIdx.z == 0) ? bias[col] : 0.f;
#pragma unroll
    for (int i = 0; i < MI; ++i) {
      const int row = m0 + wm + i * 16 + quad * 4;
#pragma unroll
      for (int r = 0; r < 4; ++r) {
        float v = acc[i][j][r] + bv;
        size_t idx = (size_t)(row + r) * ostride + ooff + col;
        if (EPI == EPI_BF16) {
          Obf[idx] = __float2bfloat16(v);
        } else if (EPI == EPI_GELU) {
          float ge = 0.5f * v * (1.f + erff(v * 0.70710678118654752f));
          Obf[idx] = __float2bfloat16(ge);
        } else if (EPI == EPI_RES) {
          Of[idx] = Orin[idx] + v;               // fused residual, race-free
        } else {
          atomicAdd(&Of[idx], v);                // fallback split-K
        }
      }
    }
  }
}

// ---------- MFMA flash attention; V from transposed VT; NO-MAX softmax ----------
// XCD-chunked: each XCD owns 2 (b,h) K/V planes -> L2-resident reads.
__global__ __launch_bounds__(256, 1) void attn_mfma(const __hip_bfloat16* __restrict__ qkv,
                                                    const __hip_bfloat16* __restrict__ VT,
                                                    __hip_bfloat16* __restrict__ ao) {
  constexpr int KPAD = 72;
  constexpr int PPAD = 40;
  __shared__ __align__(16) __hip_bfloat16 Ksh[320 * KPAD];
  __shared__ __align__(16) __hip_bfloat16 Psh[4 * 16 * PPAD];
  const int tid = threadIdx.x;
  const int wave = tid >> 6;
  const int lane = tid & 63;
  const int l15 = lane & 15;
  const int quad = lane >> 4;
  int bx, by;
  xcd_remap(bx, by);                 // grid (32,16): 512 wg, %8==0
  const int bh = by;
  const int b = bh >> 3, h = bh & 7;
  const int q0 = bx * 64;
  const int j0 = (q0 >= WWIN) ? (q0 - WWIN) : 0;   // 64-aligned
  const int nk = (q0 + 63) - j0 + 1;               // <= 320

  const size_t baseK = ((size_t)(b * TT + j0)) * 1536 + 512 + h * 64;
  for (int c = tid; c < nk * 8; c += 256) {
    int row = c >> 3, cc = (c & 7) * 8;
    *(uint4*)&Ksh[row * KPAD + cc] = *(const uint4*)&qkv[baseK + (size_t)row * 1536 + cc];
  }
  __syncthreads();

  const int qt0 = q0 + wave * 16;
  const size_t baseQ = ((size_t)(b * TT + qt0 + l15)) * 1536 + h * 64;
  const bf16x8 aq0 = *(const bf16x8*)&qkv[baseQ + quad * 8];
  const bf16x8 aq1 = *(const bf16x8*)&qkv[baseQ + 32 + quad * 8];

  const __hip_bfloat16* V0 = VT + (size_t)(h * 64 + l15) * 4096 + (size_t)b * 2048 + j0;

  f32x4 o0 = {}, o1 = {}, o2 = {}, o3 = {};
  float lsum[4] = {0.f, 0.f, 0.f, 0.f};

  const int klo = (qt0 > (WWIN - 1)) ? (qt0 - (WWIN - 1)) : 0;
  const int c_lo = (klo - j0) >> 5;
  const int c_hi = (qt0 + 15 - j0) >> 5;
  __hip_bfloat16* Pw = &Psh[wave * 16 * PPAD];

  for (int c = c_lo; c <= c_hi; ++c) {
    const int krel = c * 32;
    bf16x8 bk00 = *(const bf16x8*)&Ksh[(krel + l15) * KPAD + quad * 8];
    bf16x8 bk01 = *(const bf16x8*)&Ksh[(krel + l15) * KPAD + 32 + quad * 8];
    bf16x8 bk10 = *(const bf16x8*)&Ksh[(krel + 16 + l15) * KPAD + quad * 8];
    bf16x8 bk11 = *(const bf16x8*)&Ksh[(krel + 16 + l15) * KPAD + 32 + quad * 8];
    f32x4 z = {};
    f32x4 s0 = __builtin_amdgcn_mfma_f32_16x16x32_bf16(aq0, bk00, z, 0, 0, 0);
    s0 = __builtin_amdgcn_mfma_f32_16x16x32_bf16(aq1, bk01, s0, 0, 0, 0);
    f32x4 s1 = __builtin_amdgcn_mfma_f32_16x16x32_bf16(aq0, bk10, z, 0, 0, 0);
    s1 = __builtin_amdgcn_mfma_f32_16x16x32_bf16(aq1, bk11, s1, 0, 0, 0);

    const int jj0 = j0 + krel + l15;
    const int jj1 = jj0 + 16;
#pragma unroll
    for (int r = 0; r < 4; ++r) {
      const int qrow = qt0 + quad * 4 + r;
      const bool ok0 = (jj0 <= qrow) && ((qrow - jj0) < WWIN);
      const bool ok1 = (jj1 <= qrow) && ((qrow - jj1) < WWIN);
      const float p0 = ok0 ? __expf(s0[r] * 0.125f) : 0.f;
      const float p1 = ok1 ? __expf(s1[r] * 0.125f) : 0.f;
      lsum[r] += p0 + p1;
      const int qloc = quad * 4 + r;
      Pw[qloc * PPAD + l15]      = __float2bfloat16(p0);
      Pw[qloc * PPAD + 16 + l15] = __float2bfloat16(p1);
    }
    asm volatile("s_waitcnt lgkmcnt(0)" ::: "memory");
    __builtin_amdgcn_wave_barrier();
    const bf16x8 pa = *(const bf16x8*)&Pw[l15 * PPAD + quad * 8];

    const int kgl = krel + quad * 8;
#pragma unroll
    for (int t = 0; t < 4; ++t) {
      const bf16x8 bv = *(const bf16x8*)&V0[(size_t)t * 65536 + kgl];
      if (t == 0)      o0 = __builtin_amdgcn_mfma_f32_16x16x32_bf16(pa, bv, o0, 0, 0, 0);
      else if (t == 1) o1 = __builtin_amdgcn_mfma_f32_16x16x32_bf16(pa, bv, o1, 0, 0, 0);
      else if (t == 2) o2 = __builtin_amdgcn_mfma_f32_16x16x32_bf16(pa, bv, o2, 0, 0, 0);
      else             o3 = __builtin_amdgcn_mfma_f32_16x16x32_bf16(pa, bv, o3, 0, 0, 0);
    }
    __builtin_amdgcn_wave_barrier();
  }

#pragma unroll
  for (int r = 0; r < 4; ++r) {
#pragma unroll
    for (int off = 8; off; off >>= 1) lsum[r] += __shfl_xor(lsum[r], off, 16);
  }

#pragma unroll
  for (int r = 0; r < 4; ++r) {
    const float inv = 1.f / lsum[r];
    const size_t ob = ((size_t)(b * TT + qt0 + quad * 4 + r)) * DD + h * 64 + l15;
    ao[ob]      = __float2bfloat16(o0[r] * inv);
    ao[ob + 16] = __float2bfloat16(o1[r] * inv);
    ao[ob + 32] = __float2bfloat16(o2[r] * inv);
    ao[ob + 48] = __float2bfloat16(o3[r] * inv);
  }
}

// ---------- host launch ----------
extern "C" void kernel_launch(void* const* d_in, const int* in_sizes, int n_in,
                              void* d_out, int out_size, void* d_ws, size_t ws_size,
                              hipStream_t stream) {
  float* outF = (float*)d_out;   // fp32 output; doubles as residual x

  int code = 0;
  if (n_in != 19)                      code = 1;
  else if (in_sizes[0]  != 2097152)    code = 2;
  else if (in_sizes[1]  != 1048576)    code = 3;
  else if (in_sizes[9]  != 4194304)    code = 4;
  else if (in_sizes[17] != 512)        code = 5;
  if (code != 0 || ws_size < 27287552ull) {
    float C = code ? (150.f + 15.f * (float)code) : (1000.f + (float)(ws_size >> 20));
    fill_const<<<8192, 256, 0, stream>>>(outF, C, NOUT);
    return;
  }

  const float* tokens = (const float*)d_in[0];
  const float* Wq  = (const float*)d_in[1];
  const float* Wk  = (const float*)d_in[2];
  const float* Wv  = (const float*)d_in[3];
  const float* Wo  = (const float*)d_in[4];
  const float* bq  = (const float*)d_in[5];
  const float* bk  = (const float*)d_in[6];
  const float* bv  = (const float*)d_in[7];
  const float* bo  = (const float*)d_in[8];
  const float* W1  = (const float*)d_in[9];
  const float* b1  = (const float*)d_in[10];
  const float* W2  = (const float*)d_in[11];
  const float* b2  = (const float*)d_in[12];
  const float* g1  = (const float*)d_in[13];
  const float* be1 = (const float*)d_in[14];
  const float* g2  = (const float*)d_in[15];
  const float* be2 = (const float*)d_in[16];
  const float* gf  = (const float*)d_in[17];
  const float* bf  = (const float*)d_in[18];

  char* ws = (char*)d_ws;
  __hip_bfloat16* xnao  = (__hip_bfloat16*)(ws + 0);          //  4,194,304 (xn/ao aliased)
  __hip_bfloat16* qkv   = (__hip_bfloat16*)(ws + 4194304);    // 12,582,912
  __hip_bfloat16* hbuf  = (__hip_bfloat16*)(ws + 4194304);    // 16,777,216 span
  __hip_bfloat16* VT    = (__hip_bfloat16*)(ws + 16777216);   //  4,194,304 (attn phase only)

  const bool big = ws_size >= 46161920ull;   // hoisted transposed weights fit
  __hip_bfloat16 *wqkvT, *woT, *w1T, *w2T;
  float* bqkvc;
  if (big) {
    wqkvT = (__hip_bfloat16*)(ws + 20971520);
    woT   = (__hip_bfloat16*)(ws + 27262976);
    w1T   = (__hip_bfloat16*)(ws + 29360128);
    w2T   = (__hip_bfloat16*)(ws + 37748736);
    bqkvc = (float*)(ws + 46137344);
  } else {
    wqkvT = (__hip_bfloat16*)(ws + 20971520);
    woT   = (__hip_bfloat16*)(ws + 22544384);
    w1T   = (__hip_bfloat16*)(ws + 23068672);
    w2T   = (__hip_bfloat16*)(ws + 25165824);
    bqkvc = (float*)(ws + 27262976);
  }
  __hip_bfloat16* xn = xnao;
  __hip_bfloat16* ao = xnao;
  float* x = outF;

  if (big) {
    // ---- flow: hoisted transposes (+bias blocks), fused-residual GEMMs ----
    transpose_all<<<dim3(3078, 4), 256, 0, stream>>>(Wq, Wk, Wv, Wo, W1, W2,
                                                     wqkvT, woT, w1T, w2T,
                                                     bq, bk, bv, bqkvc);
    ln_kernel<<<1024, 256, 0, stream>>>(tokens, g1, be1, xn);
    for (int l = 0; l < LL; ++l) {
      __hip_bfloat16* qkvT_l = wqkvT + (size_t)l * 786432;
      __hip_bfloat16* woT_l  = woT   + (size_t)l * 262144;
      __hip_bfloat16* w1T_l  = w1T   + (size_t)l * 1048576;
      __hip_bfloat16* w2T_l  = w2T   + (size_t)l * 1048576;

      gemm_bt<EPI_BF16, true, 128, 64><<<dim3(24, 32), 256, 0, stream>>>(
          xn, qkvT_l, bqkvc + l * 1536, qkv, nullptr, nullptr, VT,
          MM, 1536, 512, 512, 1536, 0);
      attn_mfma<<<dim3(32, 16), 256, 0, stream>>>(qkv, VT, ao);
      // Wo: 64x64 tile, full-K, fused residual (x = xin + ao@WoT + bo)
      gemm_bt<EPI_RES, false, 64, 64><<<dim3(8, 64), 256, 0, stream>>>(
          ao, woT_l, bo + l * 512, nullptr, x, (l == 0) ? tokens : x, nullptr,
          MM, 512, 512, 512, 512, 0);
      ln_kernel<<<1024, 256, 0, stream>>>(x, g2 + l * 512, be2 + l * 512, xn);
      gemm_bt<EPI_GELU, false, 128, 128><<<dim3(16, 32), 256, 0, stream>>>(
          xn, w1T_l, b1 + l * 2048, hbuf, nullptr, nullptr, nullptr,
          MM, 2048, 512, 512, 2048, 0);
      // FFN2: 64x64 tile, full-K=2048, fused residual (x += h@W2T + b2)
      gemm_bt<EPI_RES, false, 64, 64><<<dim3(8, 64), 256, 0, stream>>>(
          hbuf, w2T_l, b2 + l * 512, nullptr, x, x, nullptr,
          MM, 512, 2048, 2048, 512, 0);
      if (l < LL - 1)
        ln_kernel<<<1024, 256, 0, stream>>>(x, g1 + (l + 1) * 512,
                                            be1 + (l + 1) * 512, xn);
      else
        ln_f32out<<<1024, 256, 0, stream>>>(x, gf, bf, outF);  // in-place safe
    }
    return;
  }

  // ---- fallback: per-layer transposes, atomic split-K ----
  prep<<<8216, 256, 0, stream>>>(tokens, x, bq, bk, bv, bqkvc);

  for (int l = 0; l < LL; ++l) {
    transpose_all<<<dim3(3072, 1), 256, 0, stream>>>(
        Wq + (size_t)l * 262144, Wk + (size_t)l * 262144, Wv + (size_t)l * 262144,
        Wo + (size_t)l * 262144, W1 + (size_t)l * 1048576, W2 + (size_t)l * 1048576,
        wqkvT, woT, w1T, w2T, bq, bk, bv, bqkvc);

    ln_kernel<<<1024, 256, 0, stream>>>(x, g1 + l * 512, be1 + l * 512, xn);
    gemm_bt<EPI_BF16, true, 128, 64><<<dim3(24, 32), 256, 0, stream>>>(
        xn, wqkvT, bqkvc + l * 1536, qkv, nullptr, nullptr, VT,
        MM, 1536, 512, 512, 1536, 0);
    attn_mfma<<<dim3(32, 16), 256, 0, stream>>>(qkv, VT, ao);
    gemm_bt<EPI_ADDF32, false, 128, 64><<<dim3(8, 32, 2), 256, 0, stream>>>(
        ao, woT, bo + l * 512, nullptr, x, nullptr, nullptr,
        MM, 512, 512, 256, 512, 0);
    ln_kernel<<<1024, 256, 0, stream>>>(x, g2 + l * 512, be2 + l * 512, xn);
    gemm_bt<EPI_GELU, false, 128, 128><<<dim3(16, 32), 256, 0, stream>>>(
        xn, w1T, b1 + l * 2048, hbuf, nullptr, nullptr, nullptr,
        MM, 2048, 512, 512, 2048, 0);
    gemm_bt<EPI_ADDF32, false, 128, 128><<<dim3(4, 32, 4), 256, 0, stream>>>(
        hbuf, w2T, b2 + l * 512, nullptr, x, nullptr, nullptr,
        MM, 512, 2048, 512, 512, 0);
  }
  ln_f32out<<<1024, 256, 0, stream>>>(x, gf, bf, outF);
}